// Round 13
// baseline (141.035 us; speedup 1.0000x reference)
//
#include <hip/hip_runtime.h>

// MpMaxPoolingMatch: out[b,t,m] = tanh( max_s sum_d lt[b,t,d]*km[m,d]*rt[b,s,d] )
// B=32, T=256, D=512, MP=20.
// R12: MX K=128 MFMA inside the compiler-proof DMA+barrier shell. R10/R11 proved the
// compiler sinks register prefetches (VGPR 84, serial L2 latency, 53us). R5 proved
// global_load_lds + barrier enforces pipelining but had only K=32 compute per drain.
// Hybrid: 4 K-steps of 128 (4 barriers), ~8x35 SIMD-cyc MFMA per wave per barrier.
// Block 64t x 128s (s-split), A-tile (lt*km -> fp8, XOR-swizzled) staged ONCE,
// B dbuf via DMA (XOR-swizzled rows, conflict-free+coalesced). LDS exactly 64KB ->
// 2 blocks/CU overlap. Partial-max + combine. fp8/MX numerics proven (R8/R10/R11).

constexpr int TT = 256;   // T
constexpr int DD = 512;   // D
constexpr int NM = 20;    // MP
constexpr int NB = 32;    // B
constexpr int NKS = 4;    // K-steps of 128

typedef float f32x4 __attribute__((ext_vector_type(4)));
typedef int   i32x8 __attribute__((ext_vector_type(8)));

__device__ __forceinline__ void async_ld16(const void* g, void* l) {
    __builtin_amdgcn_global_load_lds(
        (const __attribute__((address_space(1))) void*)g,
        (__attribute__((address_space(3))) void*)l, 16, 0, 0);
}

__device__ __forceinline__ unsigned pack_bf16(float lo, float hi) {
    unsigned ulo = __builtin_bit_cast(unsigned, lo);
    unsigned uhi = __builtin_bit_cast(unsigned, hi);
    return (ulo >> 16) | (uhi & 0xFFFF0000u);
}

// 4 fp32 -> 4 fp8 (e4m3, packed dword)
__device__ __forceinline__ unsigned pk4_fp8(float a, float b, float c, float d) {
    unsigned r = __builtin_amdgcn_cvt_pk_fp8_f32(a, b, 0, false);
    return __builtin_amdgcn_cvt_pk_fp8_f32(c, d, r, true);
}

__device__ __forceinline__ float blo(unsigned u) { return __builtin_bit_cast(float, u << 16); }
// hi bf16 without masking low bits: <0.4% relative perturbation, absorbed by fp8+tanh
__device__ __forceinline__ float bhi(unsigned u) { return __builtin_bit_cast(float, u); }

// ---------------- Phase 1: lt fp32->bf16, rt fp32->fp8, both row-major ----------------
__global__ __launch_bounds__(256)
void cast_inputs(const float* __restrict__ lt, const float* __restrict__ rt,
                 unsigned short* __restrict__ ltb, unsigned char* __restrict__ rtf)
{
    const int half = (int)gridDim.x >> 1;
    if ((int)blockIdx.x < half) {
        size_t base = ((size_t)blockIdx.x * 256 + threadIdx.x) * 8;
        float4 a = *(const float4*)(lt + base);
        float4 b = *(const float4*)(lt + base + 4);
        uint4 w;
        w.x = pack_bf16(a.x, a.y);
        w.y = pack_bf16(a.z, a.w);
        w.z = pack_bf16(b.x, b.y);
        w.w = pack_bf16(b.z, b.w);
        *(uint4*)(ltb + base) = w;
    } else {
        size_t base = ((size_t)(blockIdx.x - half) * 256 + threadIdx.x) * 8;
        float4 a = *(const float4*)(rt + base);
        float4 b = *(const float4*)(rt + base + 4);
        uint2 o;
        o.x = pk4_fp8(a.x, a.y, a.z, a.w);
        o.y = pk4_fp8(b.x, b.y, b.z, b.w);
        *(uint2*)(rtf + base) = o;
    }
}

// ---------------- Main: 64t x 128s, MX fp8 K=128, DMA+barrier, partial max ----------------
__global__ __launch_bounds__(256, 2)
void mp_match_mx(const unsigned short* __restrict__ ltb, const unsigned char* __restrict__ rtf,
                 const float* __restrict__ km, float* __restrict__ part)
{
    // pool: [0,32K) A-tile 64 rows x 32 chunks (16B), content c at pos (c&~7)|((c&7)^(r&7))
    //       [32K,64K) B dbuf: 2 x (128 rows x 8 chunks), content c at pos c^(r&7)
    //       maxbuf[4][64] aliases A after the K-loop (guarded by barrier)
    __shared__ __attribute__((aligned(16))) char pool[65536];
    uint4* Ash  = (uint4*)pool;
    uint4* Bsh0 = (uint4*)(pool + 32768);
    uint4* Bsh1 = (uint4*)(pool + 49152);
    float* maxbuf = (float*)pool;   // [4][64]

    // XCD swizzle: flat%8 == XCD; b%8 == XCD.
    const int f  = blockIdx.x;           // 0..5119
    const int c8 = f & 7;
    const int i  = f >> 3;               // 0..639
    const int b  = c8 + 8 * (i / 160);   // 0..31
    const int j  = i % 160;
    const int m  = j >> 3;               // 0..19
    const int r3 = j & 7;
    const int t0 = (r3 >> 1) * 64;       // 0,64,128,192
    const int sT = r3 & 1;
    const int s0 = sT * 128;

    const int tid  = threadIdx.x;
    const int w    = tid >> 6;
    const int lane = tid & 63;
    const int l15  = lane & 15;
    const int l4   = lane >> 4;          // k-block-of-32 within K=128
    const int ws   = w * 32;             // wave's s-slice within the 128

    const unsigned short* ltB = ltb + ((size_t)b * TT + t0) * DD;
    const unsigned char*  rtB = rtf + ((size_t)b * TT + s0) * DD;
    const float*          kmp = km  + (size_t)m * DD;

    auto issueB = [&](int kk, uint4* buf) {
#pragma unroll
        for (int q = 0; q < 4; ++q) {
            int slot = q * 256 + tid;                    // 1024 chunks of 16B
            int row  = slot >> 3;
            int cg   = (slot & 7) ^ (row & 7);           // content chunk for this slot
            async_ld16(rtB + (size_t)row * DD + kk * 128 + cg * 16,
                       (char*)buf + (size_t)slot * 16);
        }
    };

    // ---- Prologue: A lt/km loads FIRST (waitable without draining DMA), then DMA(0).
    const int cc = tid & 31, r0 = (tid >> 5) * 8;        // chunk-col, 8 rows
    uint4 h[8][2];
    {
        const unsigned short* src0 = ltB + cc * 16;
#pragma unroll
        for (int rr = 0; rr < 8; ++rr) {
            const unsigned short* s = src0 + (size_t)(r0 + rr) * DD;
            h[rr][0] = *(const uint4*)s;        // bf16 d..d+7
            h[rr][1] = *(const uint4*)(s + 8);  // bf16 d+8..d+15
        }
    }
    const float4 kA = *(const float4*)(kmp + cc * 16);
    const float4 kB = *(const float4*)(kmp + cc * 16 + 4);
    const float4 kC = *(const float4*)(kmp + cc * 16 + 8);
    const float4 kD = *(const float4*)(kmp + cc * 16 + 12);
    issueB(0, Bsh0);
#pragma unroll
    for (int rr = 0; rr < 8; ++rr) {
        uint4 h0 = h[rr][0], h1 = h[rr][1];
        uint4 o;
        o.x = pk4_fp8(blo(h0.x) * kA.x, bhi(h0.x) * kA.y, blo(h0.y) * kA.z, bhi(h0.y) * kA.w);
        o.y = pk4_fp8(blo(h0.z) * kB.x, bhi(h0.z) * kB.y, blo(h0.w) * kB.z, bhi(h0.w) * kB.w);
        o.z = pk4_fp8(blo(h1.x) * kC.x, bhi(h1.x) * kC.y, blo(h1.y) * kC.z, bhi(h1.y) * kC.w);
        o.w = pk4_fp8(blo(h1.z) * kD.x, bhi(h1.z) * kD.y, blo(h1.w) * kD.z, bhi(h1.w) * kD.w);
        const int row = r0 + rr;
        Ash[row * 32 + (cc & ~7) + ((cc & 7) ^ (row & 7))] = o;
    }

    f32x4 acc[4][2] = {};

#pragma unroll
    for (int kk = 0; kk < NKS; ++kk) {
        __syncthreads();   // A-tile + B slab(kk) ready (DMA drained); prior slab reads done
        if (kk + 1 < NKS) issueB(kk + 1, (kk & 1) ? Bsh0 : Bsh1);   // flies through MFMA
        const uint4* Bc = (kk & 1) ? Bsh1 : Bsh0;
        i32x8 av[4], bv[2];
#pragma unroll
        for (int ii = 0; ii < 4; ++ii) {
            const int row = ii * 16 + l15;
            const int base = row * 32 + kk * 8;
            ((uint4*)&av[ii])[0] = Ash[base + ((2 * l4)     ^ (row & 7))];
            ((uint4*)&av[ii])[1] = Ash[base + ((2 * l4 + 1) ^ (row & 7))];
        }
#pragma unroll
        for (int jj = 0; jj < 2; ++jj) {
            const int row = ws + jj * 16 + l15;
            ((uint4*)&bv[jj])[0] = Bc[row * 8 + ((2 * l4)     ^ (row & 7))];
            ((uint4*)&bv[jj])[1] = Bc[row * 8 + ((2 * l4 + 1) ^ (row & 7))];
        }
#pragma unroll
        for (int ii = 0; ii < 4; ++ii)
#pragma unroll
            for (int jj = 0; jj < 2; ++jj)
                acc[ii][jj] = __builtin_amdgcn_mfma_scale_f32_16x16x128_f8f6f4(
                    av[ii], bv[jj], acc[ii][jj], 0, 0, 0, 127, 0, 127);  // fmt=fp8, unit scales
    }

    __syncthreads();   // all A/B reads done before maxbuf aliases the A region

    // ---- Epilogue: max over this block's 128 s (no tanh). C: col(s)=lane&15, row(t)=(lane>>4)*4+reg.
#pragma unroll
    for (int ii = 0; ii < 4; ++ii) {
        f32x4 v = acc[ii][0];
        v.x = fmaxf(v.x, acc[ii][1].x);
        v.y = fmaxf(v.y, acc[ii][1].y);
        v.z = fmaxf(v.z, acc[ii][1].z);
        v.w = fmaxf(v.w, acc[ii][1].w);
#pragma unroll
        for (int off = 1; off < 16; off <<= 1) {
            v.x = fmaxf(v.x, __shfl_xor(v.x, off, 64));
            v.y = fmaxf(v.y, __shfl_xor(v.y, off, 64));
            v.z = fmaxf(v.z, __shfl_xor(v.z, off, 64));
            v.w = fmaxf(v.w, __shfl_xor(v.w, off, 64));
        }
        if (l15 == 0)
            *(f32x4*)&maxbuf[w * 64 + ii * 16 + l4 * 4] = v;
    }
    __syncthreads();
    if (tid < 64) {
        float v = fmaxf(fmaxf(maxbuf[tid], maxbuf[64 + tid]),
                        fmaxf(maxbuf[128 + tid], maxbuf[192 + tid]));
        part[(((size_t)sT * NB + b) * TT + t0 + tid) * NM + m] = v;
    }
}

// ---------------- Combine: out = tanh(max(p0, p1)) ----------------
__global__ __launch_bounds__(256)
void mp_combine(const float* __restrict__ part, float* __restrict__ out, int n)
{
    int idx = blockIdx.x * 256 + threadIdx.x;
    if (idx < n)
        out[idx] = tanhf(fmaxf(part[idx], part[(size_t)n + idx]));
}

// ---------------- R1 fallback (no workspace): bf16 MFMA, fp32 register staging ----------------
typedef short bf16x8 __attribute__((ext_vector_type(8)));

__global__ __launch_bounds__(256, 2)
void mp_match_kernel(const float* __restrict__ lt, const float* __restrict__ rt,
                     const float* __restrict__ km, float* __restrict__ out)
{
    __shared__ __attribute__((aligned(16))) unsigned short Ash[2][4][128][8];
    __shared__ __attribute__((aligned(16))) unsigned short Bsh2[2][4][256][8];
    __shared__ __attribute__((aligned(16))) float maxbuf[2][128];

    const int ttile = blockIdx.x, m = blockIdx.y, b = blockIdx.z;
    const int t0 = ttile * 128;
    const int tid = threadIdx.x, wave = tid >> 6, lane = tid & 63;
    const int l15 = lane & 15, l4 = lane >> 4;
    const int wt = (wave & 1) * 64, wsi = wave >> 1;

    const float* ltp = lt + ((size_t)b * TT + t0) * DD;
    const float* rtp = rt + (size_t)b * TT * DD;
    const float* kmp = km + (size_t)m * DD;
    const int a_t = tid >> 1, a_h = tid & 1;

    f32x4 acc[4][8] = {};

    auto stage = [&](int kk, int buf) {
        const int d0 = kk * 32;
        const float* ap = ltp + (size_t)a_t * DD + d0 + a_h * 16;
        const float* kp = kmp + d0 + a_h * 16;
#pragma unroll
        for (int q = 0; q < 2; ++q) {
            float4 x0 = *(const float4*)(ap + q * 8);
            float4 x1 = *(const float4*)(ap + q * 8 + 4);
            float4 k0 = *(const float4*)(kp + q * 8);
            float4 k1 = *(const float4*)(kp + q * 8 + 4);
            uint4 wv;
            wv.x = pack_bf16(x0.x * k0.x, x0.y * k0.y);
            wv.y = pack_bf16(x0.z * k0.z, x0.w * k0.w);
            wv.z = pack_bf16(x1.x * k1.x, x1.y * k1.y);
            wv.w = pack_bf16(x1.z * k1.z, x1.w * k1.w);
            *(uint4*)&Ash[buf][a_h * 2 + q][a_t][0] = wv;
        }
        const float* bp = rtp + (size_t)tid * DD + d0;
#pragma unroll
        for (int p = 0; p < 4; ++p) {
            float4 y0 = *(const float4*)(bp + p * 8);
            float4 y1 = *(const float4*)(bp + p * 8 + 4);
            uint4 wv;
            wv.x = pack_bf16(y0.x, y0.y);
            wv.y = pack_bf16(y0.z, y0.w);
            wv.z = pack_bf16(y1.x, y1.y);
            wv.w = pack_bf16(y1.z, y1.w);
            *(uint4*)&Bsh2[buf][p][tid][0] = wv;
        }
    };

    stage(0, 0);
    for (int kk = 0; kk < 16; ++kk) {
        const int buf = kk & 1;
        __syncthreads();
        bf16x8 af[4], bfv[8];
#pragma unroll
        for (int i2 = 0; i2 < 4; ++i2)
            af[i2] = *(const bf16x8*)&Ash[buf][l4][wt + i2 * 16 + l15][0];
#pragma unroll
        for (int j2 = 0; j2 < 8; ++j2)
            bfv[j2] = *(const bf16x8*)&Bsh2[buf][l4][wsi * 128 + j2 * 16 + l15][0];
        if (kk + 1 < 16) stage(kk + 1, buf ^ 1);
#pragma unroll
        for (int i2 = 0; i2 < 4; ++i2)
#pragma unroll
            for (int j2 = 0; j2 < 8; ++j2)
                acc[i2][j2] = __builtin_amdgcn_mfma_f32_16x16x32_bf16(af[i2], bfv[j2], acc[i2][j2], 0, 0, 0);
    }
#pragma unroll
    for (int i2 = 0; i2 < 4; ++i2) {
        f32x4 v = acc[i2][0];
#pragma unroll
        for (int j2 = 1; j2 < 8; ++j2) {
            v.x = fmaxf(v.x, acc[i2][j2].x); v.y = fmaxf(v.y, acc[i2][j2].y);
            v.z = fmaxf(v.z, acc[i2][j2].z); v.w = fmaxf(v.w, acc[i2][j2].w);
        }
#pragma unroll
        for (int off = 1; off < 16; off <<= 1) {
            v.x = fmaxf(v.x, __shfl_xor(v.x, off, 64));
            v.y = fmaxf(v.y, __shfl_xor(v.y, off, 64));
            v.z = fmaxf(v.z, __shfl_xor(v.z, off, 64));
            v.w = fmaxf(v.w, __shfl_xor(v.w, off, 64));
        }
        if (l15 == 0) *(f32x4*)&maxbuf[wsi][wt + i2 * 16 + l4 * 4] = v;
    }
    __syncthreads();
    if (tid < 128) {
        float v = fmaxf(maxbuf[0][tid], maxbuf[1][tid]);
        out[((size_t)b * TT + t0 + tid) * NM + m] = tanhf(v);
    }
}

extern "C" void kernel_launch(void* const* d_in, const int* in_sizes, int n_in,
                              void* d_out, int out_size, void* d_ws, size_t ws_size,
                              hipStream_t stream) {
    const float* lt  = (const float*)d_in[0];   // (32,256,512) fp32
    const float* rt  = (const float*)d_in[1];   // (32,256,512) fp32
    const float* km  = (const float*)d_in[2];   // (20,512) fp32
    float*       out = (float*)d_out;           // (32,256,20) fp32

    const size_t elems = (size_t)NB * TT * DD;                 // 4,194,304
    const size_t ltbB  = elems * sizeof(unsigned short);       // 8.39 MB bf16
    const size_t rtfB  = elems;                                // 4.19 MB fp8
    const int    nOut  = NB * TT * NM;                         // 163,840
    const size_t partB = 2 * (size_t)nOut * sizeof(float);     // 1.31 MB

    if (ws_size >= ltbB + rtfB + partB) {                      // 13.9 MB
        unsigned short* ltb = (unsigned short*)d_ws;
        unsigned char*  rtf = (unsigned char*)((char*)d_ws + ltbB);
        float* part = (float*)((char*)d_ws + ltbB + rtfB);
        cast_inputs<<<4096, 256, 0, stream>>>(lt, rt, ltb, rtf);
        mp_match_mx<<<5120, 256, 0, stream>>>(ltb, rtf, km, part);
        mp_combine<<<(nOut + 255) / 256, 256, 0, stream>>>(part, out, nOut);
    } else {
        mp_match_kernel<<<dim3(2, NM, NB), 256, 0, stream>>>(lt, rt, km, out);
    }
}